// Round 1
// baseline (2966.255 us; speedup 1.0000x reference)
//
#include <hip/hip_runtime.h>

// Problem: B=128, T=48, I=128, H=512. Sequential 48-step attention+GRU scan.
// Strategy: one persistent kernel; 8 independent batch-groups x 16 blocks;
// group-local spin barriers; fp16 MFMA (fp32 accum) for the big per-step GEMM.

typedef _Float16 half8 __attribute__((ext_vector_type(8)));
typedef _Float16 h2v  __attribute__((ext_vector_type(2)));
typedef float    f32x4 __attribute__((ext_vector_type(4)));

// ---------------- ws layout (bytes) ----------------
#define OFF_BAR   0u          // 8 groups * 128B counters (zeroed each launch)
#define OFF_BZ    4096u       // 2048 f32 : [b1 ; b_hh]
#define OFF_BC    12288u      // 1536 f32 : W_ih@b4 + b_ih
#define OFF_WZ    32768u      // 2048*512 f16 : [W1 ; W_hh] row-major
#define OFF_WCT   2129920u    // 131*1536 f16 : (W_ih@W4) transposed, k-major
#define OFF_W2H   3145728u    // 128*48*512 f16 : dx@W2^T + b2
#define OFF_HG    9437184u    // 128*512 f32 : h (master)
#define OFF_HGH   9699328u    // 128*512 f16 : h (MFMA copy)
#define OFF_ZG    9830400u    // 128*2048 f32 : z = [w1 | gh]
#define OFF_YG    10878976u   // 128*132 f32 : y = [c | x_t]

__device__ __forceinline__ float fexp2(float x) {
#if __has_builtin(__builtin_amdgcn_exp2f)
  return __builtin_amdgcn_exp2f(x);
#else
  return exp2f(x);
#endif
}
__device__ __forceinline__ float frcp(float x) {
#if __has_builtin(__builtin_amdgcn_rcpf)
  return __builtin_amdgcn_rcpf(x);
#else
  return __frcp_rn(x);
#endif
}
__device__ __forceinline__ float fast_tanh(float x) {
  x = fminf(fmaxf(x, -15.f), 15.f);
  float e = fexp2(x * 2.8853900817779268f);   // exp(2x)
  return (e - 1.f) * frcp(e + 1.f);
}
__device__ __forceinline__ float fast_sigmoid(float x) {
  x = fminf(fmaxf(x, -30.f), 30.f);
  float e = fexp2(x * 1.4426950408889634f);   // exp(x)
  return e * frcp(e + 1.f);
}

// group-local barrier: monotone counter, release-add + acquire-load spin.
// agent-scope atomics give cross-XCD visibility (LLVM emits L2 wb/inv).
__device__ __forceinline__ void group_barrier(unsigned int* ctr, unsigned int target) {
  __syncthreads();
  if (threadIdx.x == 0) {
    __hip_atomic_fetch_add(ctr, 1u, __ATOMIC_RELEASE, __HIP_MEMORY_SCOPE_AGENT);
    while (__hip_atomic_load(ctr, __ATOMIC_ACQUIRE, __HIP_MEMORY_SCOPE_AGENT) < target) {
      __builtin_amdgcn_s_sleep(2);
    }
  }
  __syncthreads();
}

// ---------------- prep 0: biases, h copies, Wz fp16, barrier zero ----------------
__global__ __launch_bounds__(256) void prep0(
    const float* __restrict__ h0, const float* __restrict__ W1,
    const float* __restrict__ Whh, const float* __restrict__ b1,
    const float* __restrict__ bhh, const float* __restrict__ Wih,
    const float* __restrict__ b4, const float* __restrict__ bih,
    float* __restrict__ hg, _Float16* __restrict__ hgh,
    _Float16* __restrict__ Wzh, float* __restrict__ bz,
    float* __restrict__ bc, unsigned int* __restrict__ bar)
{
  int idx = blockIdx.x * 256 + threadIdx.x;
  if (idx < 1024) {
    bar[idx] = 0u;
  } else if (idx < 3072) {
    int n = idx - 1024;
    bz[n] = (n < 512) ? b1[n] : bhh[n - 512];
  } else if (idx < 4608) {
    int o = idx - 3072;
    float a = bih[o];
    const float* r = Wih + o * 512;
    for (int j = 0; j < 512; ++j) a += r[j] * b4[j];
    bc[o] = a;
  } else if (idx < 4608 + 65536) {
    int i = idx - 4608;
    float v = h0[i];
    hg[i] = v;
    hgh[i] = (_Float16)v;
  } else if (idx < 70144 + 1048576) {
    int i = idx - 70144;
    int n = i >> 9, kk = i & 511;
    Wzh[i] = (_Float16)((n < 512) ? W1[i] : Whh[(n - 512) * 512 + kk]);
  }
}

// ---------------- prep 1: WcT[k][o] = (W_ih @ W4)[o][k], fp16 ----------------
__global__ __launch_bounds__(256) void prep_wc(
    const float* __restrict__ Wih, const float* __restrict__ W4,
    _Float16* __restrict__ WcT)
{
  __shared__ float wih[16 * 66];
  __shared__ float w4s[64 * 132];
  const int o0 = blockIdx.x * 16;
  const int k = threadIdx.x;
  float acc[16];
#pragma unroll
  for (int i = 0; i < 16; ++i) acc[i] = 0.f;
  for (int jc = 0; jc < 512; jc += 64) {
    __syncthreads();
    for (int idx = threadIdx.x; idx < 16 * 64; idx += 256) {
      int oo = idx >> 6, jj = idx & 63;
      wih[oo * 66 + jj] = Wih[(o0 + oo) * 512 + jc + jj];
    }
    for (int idx = threadIdx.x; idx < 64 * 131; idx += 256) {
      int r = idx / 131, c = idx - r * 131;
      w4s[r * 132 + c] = W4[(jc + r) * 131 + c];
    }
    __syncthreads();
    if (k < 131) {
      for (int jj = 0; jj < 64; ++jj) {
        float w4v = w4s[jj * 132 + k];
#pragma unroll
        for (int oo = 0; oo < 16; ++oo) acc[oo] += wih[oo * 66 + jj] * w4v;
      }
    }
  }
  if (k < 131) {
#pragma unroll
    for (int oo = 0; oo < 16; ++oo)
      WcT[k * 1536 + o0 + oo] = (_Float16)acc[oo];
  }
}

// ---------------- prep 2: w2[b][t][h] = sum_i dx[b][t][i]*W2[h][i] + b2[h], fp16 ----------------
__global__ __launch_bounds__(256) void prep_w2k(
    const float* __restrict__ dx, const float* __restrict__ W2,
    const float* __restrict__ b2, _Float16* __restrict__ w2h)
{
  const int b = blockIdx.x >> 1;
  const int th = (blockIdx.x & 1) * 24;   // t-half
  __shared__ float dxa[24 * 128];          // 12 KB
  __shared__ _Float16 w2t[128 * 132];      // 33.8 KB, [i][h_local] transposed chunk
  for (int idx = threadIdx.x; idx < 24 * 128; idx += 256)
    dxa[idx] = dx[b * 6144 + th * 128 + idx];
  for (int hc = 0; hc < 4; ++hc) {
    __syncthreads();
    for (int idx = threadIdx.x; idx < 128 * 128; idx += 256) {
      int hl = idx >> 7, i = idx & 127;
      w2t[i * 132 + hl] = (_Float16)W2[(hc * 128 + hl) * 128 + i];
    }
    __syncthreads();
    const int hh = threadIdx.x & 127;
    const int tt0 = (threadIdx.x >> 7) * 12;
    const float b2v = b2[hc * 128 + hh];
    for (int tt = tt0; tt < tt0 + 12; ++tt) {
      float acc = b2v;
#pragma unroll 4
      for (int i = 0; i < 128; ++i)
        acc += dxa[tt * 128 + i] * (float)w2t[i * 132 + hh];
      w2h[(b * 48 + th + tt) * 512 + hc * 128 + hh] = (_Float16)acc;
    }
  }
}

// ---------------- main persistent scan kernel ----------------
// grid = 128 blocks (8 groups x 16), 256 threads. Co-resident on 256 CUs.
__global__ __launch_bounds__(256) void decoder_main(
    const float* __restrict__ dx, const float* __restrict__ xin,
    const float* __restrict__ W3, const float* __restrict__ b3,
    const float* __restrict__ Wfc, const float* __restrict__ bfc,
    const _Float16* __restrict__ Wzh, const float* __restrict__ bz,
    const _Float16* __restrict__ WcT, const float* __restrict__ bc,
    const _Float16* __restrict__ w2h,
    float* __restrict__ hg, _Float16* __restrict__ hgh,
    float* __restrict__ zg, float* __restrict__ yg,
    unsigned int* __restrict__ bar, float* __restrict__ out)
{
  const int tid  = threadIdx.x;
  const int lane = tid & 63;
  const int wv   = tid >> 6;
  const int bid  = blockIdx.x;
  const int grp  = bid >> 4;     // 0..7
  const int mem  = bid & 15;     // 0..15
  const int b0   = grp * 16;     // group batch-row base
  const int myrow = b0 + mem;    // this block's ph2 row
  const int cb   = mem * 128;    // this block's ph1 column base (of 2048)
  unsigned int* ctr = bar + grp * 32;   // 128B-strided counters
  unsigned int sync_no = 0;

  __shared__ float es[48];
  __shared__ float asx[48];
  __shared__ float ygs[16 * 132];
  __shared__ float wfcs[512];
  __shared__ float red[4];

  // step-invariant per-lane data
  float w3r[8];
#pragma unroll
  for (int u = 0; u < 8; ++u) w3r[u] = W3[lane * 8 + u];
  for (int i = tid; i < 512; i += 256) wfcs[i] = Wfc[i];
  const float b3v  = b3[0];
  const float bfcv = bfc[0];

  for (int step = 0; step < 48; ++step) {
    // ---- ph1: z[16,2048] = h_g @ [W1|W_hh]^T + bz   (col-sliced, MFMA f16) ----
    {
      const int m = lane & 15, q = lane >> 4;
      const _Float16* __restrict__ hrow = hgh + (b0 + m) * 512 + q * 8;
      half8 af[16];
#pragma unroll
      for (int ks = 0; ks < 16; ++ks)
        af[ks] = *(const half8*)(hrow + ks * 32);
#pragma unroll 2
      for (int tn = 0; tn < 8; ++tn) {
        const int n = cb + tn * 16 + m;           // output col / weight row
        const _Float16* __restrict__ wrow = Wzh + n * 512 + q * 8;
        const float bzv = bz[n];
        f32x4 acc = {bzv, bzv, bzv, bzv};
#pragma unroll
        for (int ks = 0; ks < 16; ++ks) {
          half8 bf = *(const half8*)(wrow + ks * 32);
          acc = __builtin_amdgcn_mfma_f32_16x16x32_f16(af[ks], bf, acc, 0, 0, 0);
        }
#pragma unroll
        for (int r = 0; r < 4; ++r)
          zg[(b0 + q * 4 + r) * 2048 + n] = acc[r];
      }
    }
    ++sync_no; group_barrier(ctr, 16u * sync_no);   // z ready

    // ---- ph2: e -> softmax -> c  (one batch row per block) ----
    {
      const int b = myrow;
      const float* __restrict__ zrow = zg + b * 2048;
      float w1r[8];
#pragma unroll
      for (int u = 0; u < 8; ++u) w1r[u] = zrow[lane * 8 + u];
      const _Float16* __restrict__ w2row = w2h + b * 48 * 512 + lane * 8;
      for (int tt = 0; tt < 12; ++tt) {
        const int t = wv * 12 + tt;
        half8 w2v = *(const half8*)(w2row + t * 512);
        float p = 0.f;
#pragma unroll
        for (int u = 0; u < 8; ++u)
          p += w3r[u] * fast_tanh(w1r[u] + (float)w2v[u]);
#pragma unroll
        for (int off = 32; off >= 1; off >>= 1) p += __shfl_xor(p, off);
        if (lane == 0) es[t] = p + b3v;
      }
      __syncthreads();
      if (wv == 0) {
        float e = (lane < 48) ? es[lane] : -1e30f;
        float mx = e;
#pragma unroll
        for (int off = 32; off >= 1; off >>= 1) mx = fmaxf(mx, __shfl_xor(mx, off));
        float pe = (lane < 48) ? fexp2((e - mx) * 1.4426950408889634f) : 0.f;
        float s = pe;
#pragma unroll
        for (int off = 32; off >= 1; off >>= 1) s += __shfl_xor(s, off);
        float a = pe * frcp(s);
        if (lane < 48) {
          asx[lane] = a;
          if (step == 47) out[128 + b * 48 + lane] = a;   // weighted_alpha (last step)
        }
      }
      __syncthreads();
      if (tid < 128) {
        float acc = 0.f;
        const float* __restrict__ dxr = dx + b * 6144 + tid;
#pragma unroll 4
        for (int t = 0; t < 48; ++t) acc += asx[t] * dxr[t * 128];
        yg[b * 132 + tid] = acc;                 // c
      } else if (tid < 131) {
        yg[b * 132 + tid] = xin[(b * 48 + step) * 3 + (tid - 128)];  // x_t
      }
    }
    ++sync_no; group_barrier(ctr, 16u * sync_no);   // y=[c|x_t] ready

    // ---- ph3: gi = y@Wc^T + bc ; GRU gates ; h_new  (col-sliced, all 16 rows) ----
    {
      for (int i = tid; i < 16 * 132; i += 256) ygs[i] = yg[b0 * 132 + i];
      __syncthreads();
      const int m  = tid >> 4;           // row 0..15
      const int cg = tid & 15;           // col-pair 0..15
      const int c0 = mem * 32 + cg * 2;  // h-col pair base (this block owns 32 h-cols)
      float a0 = bc[c0],        a1 = bc[c0 + 1];
      float a2 = bc[512 + c0],  a3 = bc[512 + c0 + 1];
      float a4 = bc[1024 + c0], a5 = bc[1024 + c0 + 1];
      const float* __restrict__ yrow = ygs + m * 132;
#pragma unroll 4
      for (int k = 0; k < 131; ++k) {
        const float yk = yrow[k];
        const _Float16* __restrict__ wr = WcT + k * 1536 + c0;
        h2v w0 = *(const h2v*)(wr);
        h2v w1v = *(const h2v*)(wr + 512);
        h2v w2v = *(const h2v*)(wr + 1024);
        a0 += yk * (float)w0[0];  a1 += yk * (float)w0[1];
        a2 += yk * (float)w1v[0]; a3 += yk * (float)w1v[1];
        a4 += yk * (float)w2v[0]; a5 += yk * (float)w2v[1];
      }
      const int b = b0 + m;
      const float* __restrict__ zrow = zg + b * 2048;
      const float hr0 = zrow[512 + c0],  hr1 = zrow[513 + c0];
      const float hz0 = zrow[1024 + c0], hz1 = zrow[1025 + c0];
      const float hn0 = zrow[1536 + c0], hn1 = zrow[1537 + c0];
      const float ho0 = hg[b * 512 + c0], ho1 = hg[b * 512 + c0 + 1];
      const float r0 = fast_sigmoid(a0 + hr0), r1 = fast_sigmoid(a1 + hr1);
      const float z0 = fast_sigmoid(a2 + hz0), z1 = fast_sigmoid(a3 + hz1);
      const float n0 = fast_tanh(a4 + r0 * hn0), n1 = fast_tanh(a5 + r1 * hn1);
      const float hN0 = (1.f - z0) * n0 + z0 * ho0;
      const float hN1 = (1.f - z1) * n1 + z1 * ho1;
      hg[b * 512 + c0] = hN0;
      hg[b * 512 + c0 + 1] = hN1;
      h2v hp; hp[0] = (_Float16)hN0; hp[1] = (_Float16)hN1;
      *(h2v*)(hgh + b * 512 + c0) = hp;
    }
    ++sync_no; group_barrier(ctr, 16u * sync_no);   // h_new ready
  }

  // ---- epilogue: re[b] = h_f[b] . Wfc + bfc ----
  {
    const int b = myrow;
    float p = hg[b * 512 + tid] * wfcs[tid] + hg[b * 512 + 256 + tid] * wfcs[256 + tid];
#pragma unroll
    for (int off = 32; off >= 1; off >>= 1) p += __shfl_xor(p, off);
    if (lane == 0) red[wv] = p;
    __syncthreads();
    if (tid == 0) out[b] = red[0] + red[1] + red[2] + red[3] + bfcv;
  }
}

extern "C" void kernel_launch(void* const* d_in, const int* in_sizes, int n_in,
                              void* d_out, int out_size, void* d_ws, size_t ws_size,
                              hipStream_t stream) {
  (void)in_sizes; (void)n_in; (void)out_size; (void)ws_size;
  const float* dx  = (const float*)d_in[0];
  const float* xin = (const float*)d_in[1];
  const float* h0  = (const float*)d_in[2];
  const float* W1  = (const float*)d_in[3];
  const float* b1  = (const float*)d_in[4];
  const float* W2  = (const float*)d_in[5];
  const float* b2  = (const float*)d_in[6];
  const float* W3  = (const float*)d_in[7];
  const float* b3  = (const float*)d_in[8];
  const float* W4  = (const float*)d_in[9];
  const float* b4  = (const float*)d_in[10];
  const float* Wih = (const float*)d_in[11];
  const float* Whh = (const float*)d_in[12];
  const float* bih = (const float*)d_in[13];
  const float* bhh = (const float*)d_in[14];
  const float* Wfc = (const float*)d_in[15];
  const float* bfc = (const float*)d_in[16];

  char* ws = (char*)d_ws;
  unsigned int* bar = (unsigned int*)(ws + OFF_BAR);
  float*     bz  = (float*)(ws + OFF_BZ);
  float*     bc  = (float*)(ws + OFF_BC);
  _Float16*  Wzh = (_Float16*)(ws + OFF_WZ);
  _Float16*  WcT = (_Float16*)(ws + OFF_WCT);
  _Float16*  w2h = (_Float16*)(ws + OFF_W2H);
  float*     hg  = (float*)(ws + OFF_HG);
  _Float16*  hgh = (_Float16*)(ws + OFF_HGH);
  float*     zg  = (float*)(ws + OFF_ZG);
  float*     yg  = (float*)(ws + OFF_YG);

  prep0<<<4370, 256, 0, stream>>>(h0, W1, Whh, b1, bhh, Wih, b4, bih,
                                  hg, hgh, Wzh, bz, bc, bar);
  prep_wc<<<96, 256, 0, stream>>>(Wih, W4, WcT);
  prep_w2k<<<256, 256, 0, stream>>>(dx, W2, b2, w2h);
  decoder_main<<<128, 256, 0, stream>>>(dx, xin, W3, b3, Wfc, bfc,
                                        Wzh, bz, WcT, bc, w2h,
                                        hg, hgh, zg, yg, bar, (float*)d_out);
}

// Round 3
// 1958.076 us; speedup vs baseline: 1.5149x; 1.5149x over previous
//
#include <hip/hip_runtime.h>

// B=128, T=48, I=128, H=512. Sequential 48-step attention+GRU scan.
// One persistent kernel; 8 groups x 16 blocks (groups XCD-local under
// round-robin dispatch heuristic: grp = bid & 7). Cross-block data moves via
// relaxed agent-scope atomic load/store (sc-flagged, LLC-coherent, NO cache
// maintenance). Barrier: release RMW (cheap: no dirty comm lines) + relaxed
// spin + compiler fences. Read-only weights stay hot in per-XCD L2.

typedef _Float16 half8 __attribute__((ext_vector_type(8)));
typedef _Float16 h2v  __attribute__((ext_vector_type(2)));
typedef float    f32x4 __attribute__((ext_vector_type(4)));

// ---------------- ws layout (bytes) ----------------
#define OFF_BAR   0u          // 8 groups * 128B counters (zeroed each launch)
#define OFF_BZ    4096u       // 2048 f32 : [b1 ; b_hh]
#define OFF_BC    12288u      // 1536 f32 : W_ih@b4 + b_ih
#define OFF_WZ    32768u      // 2048*512 f16 : [W1 ; W_hh] row-major
#define OFF_WCT   2129920u    // 131*1536 f16 : (W_ih@W4) transposed, k-major
#define OFF_W2H   3145728u    // 128*48*512 f16 : dx@W2^T + b2
#define OFF_HG    9437184u    // 128*512 f32 : h (master, block-private cols)
#define OFF_HGH   9699328u    // 128*512 f16 : h (MFMA copy, cross-block)
#define OFF_ZG    9830400u    // 128*2048 f32 : z = [w1 | gh]
#define OFF_YG    10878976u   // 128*132 f32 : y = [c | x_t]

__device__ __forceinline__ float fexp2(float x) { return __builtin_amdgcn_exp2f(x); }
__device__ __forceinline__ float frcp(float x)  { return __builtin_amdgcn_rcpf(x); }
__device__ __forceinline__ float fast_tanh(float x) {
  x = fminf(fmaxf(x, -15.f), 15.f);
  float e = fexp2(x * 2.8853900817779268f);   // exp(2x)
  return (e - 1.f) * frcp(e + 1.f);
}
__device__ __forceinline__ float fast_sigmoid(float x) {
  x = fminf(fmaxf(x, -30.f), 30.f);
  float e = fexp2(x * 1.4426950408889634f);   // exp(x)
  return e * frcp(e + 1.f);
}

// ---- coherent (agent-scope, per-access) data movement: no cache maintenance ----
__device__ __forceinline__ void st_f32(float* p, float v) {
  __hip_atomic_store(p, v, __ATOMIC_RELAXED, __HIP_MEMORY_SCOPE_AGENT);
}
__device__ __forceinline__ float ld_f32(const float* p) {
  return __hip_atomic_load(p, __ATOMIC_RELAXED, __HIP_MEMORY_SCOPE_AGENT);
}
__device__ __forceinline__ unsigned long long ld_u64(const void* p) {
  return __hip_atomic_load((const unsigned long long*)p, __ATOMIC_RELAXED,
                           __HIP_MEMORY_SCOPE_AGENT);
}
__device__ __forceinline__ void st_u32(unsigned int* p, unsigned int v) {
  __hip_atomic_store(p, v, __ATOMIC_RELAXED, __HIP_MEMORY_SCOPE_AGENT);
}
union U2 { unsigned long long u; float f[2]; };
union HU { unsigned int u; h2v h; };

// Group barrier: release RMW (vmcnt drain + wbl2; no dirty comm lines so
// cheap) + RELAXED spin (no L2 invalidate — the R1 perf killer) + compiler
// fences. Monotone counter; spurious re-polls benign.
__device__ __forceinline__ void group_barrier(unsigned int* ctr, unsigned int target) {
  __syncthreads();
  if (threadIdx.x == 0) {
    __hip_atomic_fetch_add(ctr, 1u, __ATOMIC_RELEASE, __HIP_MEMORY_SCOPE_AGENT);
    while (__hip_atomic_load(ctr, __ATOMIC_RELAXED, __HIP_MEMORY_SCOPE_AGENT) < target) {
      __builtin_amdgcn_s_sleep(2);
    }
    __asm__ __volatile__("" ::: "memory");
  }
  __syncthreads();
}

// ---------------- prep 0: biases, h copies, Wz fp16, barrier zero ----------------
__global__ __launch_bounds__(256) void prep0(
    const float* __restrict__ h0, const float* __restrict__ W1,
    const float* __restrict__ Whh, const float* __restrict__ b1,
    const float* __restrict__ bhh, const float* __restrict__ Wih,
    const float* __restrict__ b4, const float* __restrict__ bih,
    float* __restrict__ hg, _Float16* __restrict__ hgh,
    _Float16* __restrict__ Wzh, float* __restrict__ bz,
    float* __restrict__ bc, unsigned int* __restrict__ bar)
{
  int idx = blockIdx.x * 256 + threadIdx.x;
  if (idx < 1024) {
    bar[idx] = 0u;
  } else if (idx < 3072) {
    int n = idx - 1024;
    bz[n] = (n < 512) ? b1[n] : bhh[n - 512];
  } else if (idx < 4608) {
    int o = idx - 3072;
    float a = bih[o];
    const float* r = Wih + o * 512;
    for (int j = 0; j < 512; ++j) a += r[j] * b4[j];
    bc[o] = a;
  } else if (idx < 4608 + 65536) {
    int i = idx - 4608;
    float v = h0[i];
    hg[i] = v;
    hgh[i] = (_Float16)v;
  } else if (idx < 70144 + 1048576) {
    int i = idx - 70144;
    int n = i >> 9, kk = i & 511;
    Wzh[i] = (_Float16)((n < 512) ? W1[i] : Whh[(n - 512) * 512 + kk]);
  }
}

// ---------------- prep 1: WcT[k][o] = (W_ih @ W4)[o][k], fp16 ----------------
__global__ __launch_bounds__(256) void prep_wc(
    const float* __restrict__ Wih, const float* __restrict__ W4,
    _Float16* __restrict__ WcT)
{
  __shared__ float wih[16 * 66];
  __shared__ float w4s[64 * 132];
  const int o0 = blockIdx.x * 16;
  const int k = threadIdx.x;
  float acc[16];
#pragma unroll
  for (int i = 0; i < 16; ++i) acc[i] = 0.f;
  for (int jc = 0; jc < 512; jc += 64) {
    __syncthreads();
    for (int idx = threadIdx.x; idx < 16 * 64; idx += 256) {
      int oo = idx >> 6, jj = idx & 63;
      wih[oo * 66 + jj] = Wih[(o0 + oo) * 512 + jc + jj];
    }
    for (int idx = threadIdx.x; idx < 64 * 131; idx += 256) {
      int r = idx / 131, c = idx - r * 131;
      w4s[r * 132 + c] = W4[(jc + r) * 131 + c];
    }
    __syncthreads();
    if (k < 131) {
      for (int jj = 0; jj < 64; ++jj) {
        float w4v = w4s[jj * 132 + k];
#pragma unroll
        for (int oo = 0; oo < 16; ++oo) acc[oo] += wih[oo * 66 + jj] * w4v;
      }
    }
  }
  if (k < 131) {
#pragma unroll
    for (int oo = 0; oo < 16; ++oo)
      WcT[k * 1536 + o0 + oo] = (_Float16)acc[oo];
  }
}

// ---------------- prep 2: w2[b][t][h] = dx@W2^T + b2, fp16 ----------------
__global__ __launch_bounds__(256) void prep_w2k(
    const float* __restrict__ dx, const float* __restrict__ W2,
    const float* __restrict__ b2, _Float16* __restrict__ w2h)
{
  const int b = blockIdx.x >> 1;
  const int th = (blockIdx.x & 1) * 24;   // t-half
  __shared__ float dxa[24 * 128];
  __shared__ _Float16 w2t[128 * 132];
  for (int idx = threadIdx.x; idx < 24 * 128; idx += 256)
    dxa[idx] = dx[b * 6144 + th * 128 + idx];
  for (int hc = 0; hc < 4; ++hc) {
    __syncthreads();
    for (int idx = threadIdx.x; idx < 128 * 128; idx += 256) {
      int hl = idx >> 7, i = idx & 127;
      w2t[i * 132 + hl] = (_Float16)W2[(hc * 128 + hl) * 128 + i];
    }
    __syncthreads();
    const int hh = threadIdx.x & 127;
    const int tt0 = (threadIdx.x >> 7) * 12;
    const float b2v = b2[hc * 128 + hh];
    for (int tt = tt0; tt < tt0 + 12; ++tt) {
      float acc = b2v;
#pragma unroll 4
      for (int i = 0; i < 128; ++i)
        acc += dxa[tt * 128 + i] * (float)w2t[i * 132 + hh];
      w2h[(b * 48 + th + tt) * 512 + hc * 128 + hh] = (_Float16)acc;
    }
  }
}

// ---------------- main persistent scan kernel ----------------
// grid = 128 blocks (8 groups x 16), 256 threads.
__global__ __launch_bounds__(256) void decoder_main(
    const float* __restrict__ dx, const float* __restrict__ xin,
    const float* __restrict__ W3, const float* __restrict__ b3,
    const float* __restrict__ Wfc, const float* __restrict__ bfc,
    const _Float16* __restrict__ Wzh, const float* __restrict__ bz,
    const _Float16* __restrict__ WcT, const float* __restrict__ bc,
    const _Float16* __restrict__ w2h,
    float* __restrict__ hg, _Float16* __restrict__ hgh,
    float* __restrict__ zg, float* __restrict__ yg,
    unsigned int* __restrict__ bar, float* __restrict__ out)
{
  const int tid  = threadIdx.x;
  const int lane = tid & 63;
  const int wv   = tid >> 6;
  const int bid  = blockIdx.x;
  const int grp  = bid & 7;      // XCD-local group under round-robin dispatch
  const int mem  = bid >> 3;     // 0..15
  const int b0   = grp * 16;     // group batch-row base
  const int myrow = b0 + mem;    // this block's ph2 row
  const int cb   = mem * 128;    // this block's ph1 column base (of 2048)
  unsigned int* ctr = bar + grp * 32;
  unsigned int sync_no = 0;

  __shared__ _Float16 hsh[16][520];   // staged h group slice (stride 520: 2-way banks)
  __shared__ float es[48];
  __shared__ float asx[48];
  __shared__ float ygs[16 * 132];
  __shared__ float wfcs[512];
  __shared__ float red[4];

  float w3r[8];
#pragma unroll
  for (int u = 0; u < 8; ++u) w3r[u] = W3[lane * 8 + u];
  for (int i = tid; i < 512; i += 256) wfcs[i] = Wfc[i];
  const float b3v  = b3[0];
  const float bfcv = bfc[0];

  for (int step = 0; step < 48; ++step) {
    // ---- stage h (f16) group slice into LDS: 16 rows x 512 halves (128 u64/row) ----
    for (int i = tid; i < 16 * 128; i += 256) {
      int r = i >> 7, c = i & 127;         // c: u64 chunk = 4 halves
      unsigned long long u = ld_u64(hgh + (b0 + r) * 512 + c * 4);
      *(unsigned long long*)(&hsh[r][c * 4]) = u;
    }
    __syncthreads();

    // ---- ph1: z[16,2048] = h @ [W1|W_hh]^T + bz (col-sliced, wave-split MFMA) ----
    {
      const int m = lane & 15, q = lane >> 4;
      half8 af[16];
#pragma unroll
      for (int ks = 0; ks < 16; ++ks)
        af[ks] = *(const half8*)(&hsh[m][q * 8 + ks * 32]);
#pragma unroll
      for (int tn2 = 0; tn2 < 2; ++tn2) {
        const int n = cb + (wv * 2 + tn2) * 16 + m;   // output col / weight row
        const _Float16* __restrict__ wrow = Wzh + n * 512 + q * 8;
        const float bzv = bz[n];
        f32x4 acc = {bzv, bzv, bzv, bzv};
#pragma unroll
        for (int ks = 0; ks < 16; ++ks) {
          half8 bf = *(const half8*)(wrow + ks * 32);
          acc = __builtin_amdgcn_mfma_f32_16x16x32_f16(af[ks], bf, acc, 0, 0, 0);
        }
#pragma unroll
        for (int r = 0; r < 4; ++r)
          st_f32(&zg[(b0 + q * 4 + r) * 2048 + n], acc[r]);
      }
    }
    ++sync_no; group_barrier(ctr, 16u * sync_no);   // z ready

    // ---- ph2: e -> softmax -> c  (one batch row per block) ----
    {
      const int b = myrow;
      const float* __restrict__ zrow = zg + b * 2048;
      float w1r[8];
#pragma unroll
      for (int u2 = 0; u2 < 4; ++u2) {
        U2 t; t.u = ld_u64(zrow + lane * 8 + u2 * 2);
        w1r[u2 * 2] = t.f[0]; w1r[u2 * 2 + 1] = t.f[1];
      }
      const _Float16* __restrict__ w2row = w2h + b * 48 * 512 + lane * 8;
      for (int tt = 0; tt < 12; ++tt) {
        const int t = wv * 12 + tt;
        half8 w2v = *(const half8*)(w2row + t * 512);
        float p = 0.f;
#pragma unroll
        for (int u = 0; u < 8; ++u)
          p += w3r[u] * fast_tanh(w1r[u] + (float)w2v[u]);
#pragma unroll
        for (int off = 32; off >= 1; off >>= 1) p += __shfl_xor(p, off);
        if (lane == 0) es[t] = p + b3v;
      }
      __syncthreads();
      if (wv == 0) {
        float e = (lane < 48) ? es[lane] : -1e30f;
        float mx = e;
#pragma unroll
        for (int off = 32; off >= 1; off >>= 1) mx = fmaxf(mx, __shfl_xor(mx, off));
        float pe = (lane < 48) ? fexp2((e - mx) * 1.4426950408889634f) : 0.f;
        float s = pe;
#pragma unroll
        for (int off = 32; off >= 1; off >>= 1) s += __shfl_xor(s, off);
        float a = pe * frcp(s);
        if (lane < 48) {
          asx[lane] = a;
          if (step == 47) out[128 + b * 48 + lane] = a;   // alpha (last step)
        }
      }
      __syncthreads();
      if (tid < 128) {
        float acc = 0.f;
        const float* __restrict__ dxr = dx + b * 6144 + tid;
#pragma unroll 4
        for (int t = 0; t < 48; ++t) acc += asx[t] * dxr[t * 128];
        st_f32(&yg[b * 132 + tid], acc);                 // c
      } else if (tid < 131) {
        st_f32(&yg[b * 132 + tid], xin[(b * 48 + step) * 3 + (tid - 128)]);  // x_t
      }
    }
    ++sync_no; group_barrier(ctr, 16u * sync_no);   // y=[c|x_t] ready

    // ---- ph3: gi = y@Wc^T + bc ; GRU gates ; h_new (col-sliced) ----
    {
      for (int i = tid; i < 16 * 66; i += 256) {
        unsigned long long u = ld_u64(yg + b0 * 132 + i * 2);
        *(unsigned long long*)&ygs[i * 2] = u;
      }
      __syncthreads();
      const int m  = tid >> 4;           // row 0..15
      const int cg = tid & 15;           // col-pair 0..15
      const int c0 = mem * 32 + cg * 2;  // this block owns h-cols [mem*32, +32)
      float a0 = bc[c0],        a1 = bc[c0 + 1];
      float a2 = bc[512 + c0],  a3 = bc[512 + c0 + 1];
      float a4 = bc[1024 + c0], a5 = bc[1024 + c0 + 1];
      const float* __restrict__ yrow = ygs + m * 132;
#pragma unroll 4
      for (int k = 0; k < 131; ++k) {
        const float yk = yrow[k];
        const _Float16* __restrict__ wr = WcT + k * 1536 + c0;
        h2v w0 = *(const h2v*)(wr);
        h2v w1v = *(const h2v*)(wr + 512);
        h2v w2v = *(const h2v*)(wr + 1024);
        a0 += yk * (float)w0[0];  a1 += yk * (float)w0[1];
        a2 += yk * (float)w1v[0]; a3 += yk * (float)w1v[1];
        a4 += yk * (float)w2v[0]; a5 += yk * (float)w2v[1];
      }
      const int b = b0 + m;
      const float* __restrict__ zrow = zg + b * 2048;
      U2 tr, tz, tn2, th2;
      tr.u  = ld_u64(zrow + 512 + c0);
      tz.u  = ld_u64(zrow + 1024 + c0);
      tn2.u = ld_u64(zrow + 1536 + c0);
      th2.u = *(const unsigned long long*)(hg + b * 512 + c0);  // block-private
      const float r0 = fast_sigmoid(a0 + tr.f[0]), r1 = fast_sigmoid(a1 + tr.f[1]);
      const float z0 = fast_sigmoid(a2 + tz.f[0]), z1 = fast_sigmoid(a3 + tz.f[1]);
      const float n0 = fast_tanh(a4 + r0 * tn2.f[0]), n1 = fast_tanh(a5 + r1 * tn2.f[1]);
      const float hN0 = (1.f - z0) * n0 + z0 * th2.f[0];
      const float hN1 = (1.f - z1) * n1 + z1 * th2.f[1];
      st_f32(hg + b * 512 + c0, hN0);
      st_f32(hg + b * 512 + c0 + 1, hN1);
      HU hp; hp.h[0] = (_Float16)hN0; hp.h[1] = (_Float16)hN1;
      st_u32((unsigned int*)(hgh + b * 512 + c0), hp.u);
    }
    ++sync_no; group_barrier(ctr, 16u * sync_no);   // h_new ready
  }

  // ---- epilogue: re[b] = h_f[b] . Wfc + bfc ----
  {
    const int b = myrow;
    float p = ld_f32(hg + b * 512 + tid) * wfcs[tid]
            + ld_f32(hg + b * 512 + 256 + tid) * wfcs[256 + tid];
#pragma unroll
    for (int off = 32; off >= 1; off >>= 1) p += __shfl_xor(p, off);
    if (lane == 0) red[wv] = p;
    __syncthreads();
    if (tid == 0) out[b] = red[0] + red[1] + red[2] + red[3] + bfcv;
  }
}

extern "C" void kernel_launch(void* const* d_in, const int* in_sizes, int n_in,
                              void* d_out, int out_size, void* d_ws, size_t ws_size,
                              hipStream_t stream) {
  (void)in_sizes; (void)n_in; (void)out_size; (void)ws_size;
  const float* dx  = (const float*)d_in[0];
  const float* xin = (const float*)d_in[1];
  const float* h0  = (const float*)d_in[2];
  const float* W1  = (const float*)d_in[3];
  const float* b1  = (const float*)d_in[4];
  const float* W2  = (const float*)d_in[5];
  const float* b2  = (const float*)d_in[6];
  const float* W3  = (const float*)d_in[7];
  const float* b3  = (const float*)d_in[8];
  const float* W4  = (const float*)d_in[9];
  const float* b4  = (const float*)d_in[10];
  const float* Wih = (const float*)d_in[11];
  const float* Whh = (const float*)d_in[12];
  const float* bih = (const float*)d_in[13];
  const float* bhh = (const float*)d_in[14];
  const float* Wfc = (const float*)d_in[15];
  const float* bfc = (const float*)d_in[16];

  char* ws = (char*)d_ws;
  unsigned int* bar = (unsigned int*)(ws + OFF_BAR);
  float*     bz  = (float*)(ws + OFF_BZ);
  float*     bc  = (float*)(ws + OFF_BC);
  _Float16*  Wzh = (_Float16*)(ws + OFF_WZ);
  _Float16*  WcT = (_Float16*)(ws + OFF_WCT);
  _Float16*  w2h = (_Float16*)(ws + OFF_W2H);
  float*     hg  = (float*)(ws + OFF_HG);
  _Float16*  hgh = (_Float16*)(ws + OFF_HGH);
  float*     zg  = (float*)(ws + OFF_ZG);
  float*     yg  = (float*)(ws + OFF_YG);

  prep0<<<4370, 256, 0, stream>>>(h0, W1, Whh, b1, bhh, Wih, b4, bih,
                                  hg, hgh, Wzh, bz, bc, bar);
  prep_wc<<<96, 256, 0, stream>>>(Wih, W4, WcT);
  prep_w2k<<<256, 256, 0, stream>>>(dx, W2, b2, w2h);
  decoder_main<<<128, 256, 0, stream>>>(dx, xin, W3, b3, Wfc, bfc,
                                        Wzh, bz, WcT, bc, w2h,
                                        hg, hgh, zg, yg, bar, (float*)d_out);
}

// Round 4
// 1825.767 us; speedup vs baseline: 1.6247x; 1.0725x over previous
//
#include <hip/hip_runtime.h>

// B=128, T=48, I=128, H=512. Sequential 48-step attention+GRU scan.
// Persistent kernel: 8 groups x 16 blocks (grp = bid&7: XCD-local heuristic).
// R4: flag-array barrier (no RMW contention, lane-parallel poll),
//     register-persistent Wz MFMA B-fragments, no LDS h-tile, fused prep.

typedef _Float16 half8 __attribute__((ext_vector_type(8)));
typedef _Float16 h2v  __attribute__((ext_vector_type(2)));
typedef float    f32x4 __attribute__((ext_vector_type(4)));

// ---------------- ws layout (bytes) ----------------
#define OFF_BAR   0u          // 128 flags * 128B (zeroed by prep)
#define OFF_BZ    32768u      // 2048 f32 : [b1 ; b_hh]
#define OFF_BC    40960u      // 1536 f32 : W_ih@b4 + b_ih
#define OFF_WZ    65536u      // 2048*512 f16 : [W1 ; W_hh] row-major
#define OFF_WCT   2162688u    // 131*1536 f16 : (W_ih@W4)^T, k-major
#define OFF_W2H   3178496u    // 128*48*512 f16 : dx@W2^T + b2
#define OFF_HG    9469952u    // 128*512 f32 : h (block-private cols)
#define OFF_HGH   9732096u    // 128*512 f16 : h (cross-block copy)
#define OFF_ZG    9863168u    // 128*2048 f32 : z = [w1 | gh]
#define OFF_YG    10911744u   // 128*132 f32 : y = [c | x_t]

__device__ __forceinline__ float fexp2(float x) { return __builtin_amdgcn_exp2f(x); }
__device__ __forceinline__ float frcp(float x)  { return __builtin_amdgcn_rcpf(x); }
__device__ __forceinline__ float fast_tanh(float x) {
  x = fminf(fmaxf(x, -15.f), 15.f);
  float e = fexp2(x * 2.8853900817779268f);   // exp(2x)
  return (e - 1.f) * frcp(e + 1.f);
}
__device__ __forceinline__ float fast_sigmoid(float x) {
  x = fminf(fmaxf(x, -30.f), 30.f);
  float e = fexp2(x * 1.4426950408889634f);   // exp(x)
  return e * frcp(e + 1.f);
}

// ---- coherent (agent-scope, per-access) data movement ----
__device__ __forceinline__ void st_f32(float* p, float v) {
  __hip_atomic_store(p, v, __ATOMIC_RELAXED, __HIP_MEMORY_SCOPE_AGENT);
}
__device__ __forceinline__ unsigned long long ld_u64(const void* p) {
  return __hip_atomic_load((const unsigned long long*)p, __ATOMIC_RELAXED,
                           __HIP_MEMORY_SCOPE_AGENT);
}
__device__ __forceinline__ unsigned int ld_u32(const void* p) {
  return __hip_atomic_load((const unsigned int*)p, __ATOMIC_RELAXED,
                           __HIP_MEMORY_SCOPE_AGENT);
}
__device__ __forceinline__ void st_u32(unsigned int* p, unsigned int v) {
  __hip_atomic_store(p, v, __ATOMIC_RELAXED, __HIP_MEMORY_SCOPE_AGENT);
}
union U2 { unsigned long long u; float f[2]; };
union H8 { unsigned long long u[2]; half8 h; };
union HU { unsigned int u; h2v h; };
union H4 { unsigned long long u; _Float16 h[4]; };

// Flag-array barrier: each block release-stores its own flag line (128B apart);
// wave 0 polls all 16 flags with ONE lane-parallel load + ballot. No RMW, no
// shared-line writers -> no coherence-point serialization.
__device__ __forceinline__ void flag_barrier(unsigned int* flags, int myIdx,
                                             int base16, unsigned int target,
                                             int tid, int lane, int wv) {
  __syncthreads();   // all block stores drained (vmcnt0 before s_barrier)
  if (tid == 0)
    __hip_atomic_store(flags + myIdx * 32, target, __ATOMIC_RELEASE,
                       __HIP_MEMORY_SCOPE_AGENT);
  if (wv == 0) {
    unsigned int* fp = flags + (base16 + (lane & 15)) * 32;
    for (;;) {
      unsigned int v = (lane < 16)
        ? __hip_atomic_load(fp, __ATOMIC_RELAXED, __HIP_MEMORY_SCOPE_AGENT)
        : target;
      if ((__ballot(v < target) & 0xFFFFull) == 0) break;
      __builtin_amdgcn_s_sleep(1);
    }
    __asm__ __volatile__("" ::: "memory");
  }
  __syncthreads();
}

// ---------------- fused prep kernel (grid 322 x 256) ----------------
__global__ __launch_bounds__(256) void prep_all(
    const float* __restrict__ dx, const float* __restrict__ h0,
    const float* __restrict__ W1, const float* __restrict__ Whh,
    const float* __restrict__ b1, const float* __restrict__ bhh,
    const float* __restrict__ Wih, const float* __restrict__ W4,
    const float* __restrict__ b4, const float* __restrict__ bih,
    const float* __restrict__ W2, const float* __restrict__ b2,
    float* __restrict__ hg, _Float16* __restrict__ hgh,
    _Float16* __restrict__ Wzh, float* __restrict__ bz,
    float* __restrict__ bc, _Float16* __restrict__ WcT,
    _Float16* __restrict__ w2h, unsigned int* __restrict__ bar)
{
  __shared__ __align__(16) char smem[58368];
  const int bid = blockIdx.x;
  const int tid = threadIdx.x;
  const int lane = tid & 63, wv = tid >> 6;

  if (bid == 0) {                       // zero flag region (8192 u32)
    for (int i = tid; i < 8192; i += 256) bar[i] = 0u;
  } else if (bid == 1) {                // bz
    for (int n = tid; n < 2048; n += 256)
      bz[n] = (n < 512) ? b1[n] : bhh[n - 512];
  } else if (bid < 18) {                // bc: 16 blocks x 96 rows, wave/row
    const int o0 = (bid - 2) * 96 + wv * 24;
    for (int it = 0; it < 24; ++it) {
      const int row = o0 + it;
      const float* r = Wih + row * 512 + lane * 8;
      float s = 0.f;
#pragma unroll
      for (int u = 0; u < 8; ++u) s += r[u] * b4[lane * 8 + u];
#pragma unroll
      for (int off = 32; off >= 1; off >>= 1) s += __shfl_xor(s, off);
      if (lane == 0) bc[row] = bih[row] + s;
    }
  } else if (bid < 34) {                // hg / hgh init
    const int i0 = (bid - 18) * 4096 + tid * 16;
#pragma unroll
    for (int u = 0; u < 4; ++u) {
      float4 v = *(const float4*)(h0 + i0 + u * 4);
      *(float4*)(hg + i0 + u * 4) = v;
      H4 p; p.h[0] = (_Float16)v.x; p.h[1] = (_Float16)v.y;
      p.h[2] = (_Float16)v.z; p.h[3] = (_Float16)v.w;
      *(unsigned long long*)(hgh + i0 + u * 4) = p.u;
    }
  } else if (bid < 98) {                // Wzh = f16([W1;Whh]) flat copy
    const int i0 = (bid - 34) * 16384 + tid * 64;
#pragma unroll 4
    for (int u = 0; u < 16; ++u) {
      const int i = i0 + u * 4;
      const float* src = (i < 262144) ? (W1 + i) : (Whh + i - 262144);
      float4 v = *(const float4*)src;
      H4 p; p.h[0] = (_Float16)v.x; p.h[1] = (_Float16)v.y;
      p.h[2] = (_Float16)v.z; p.h[3] = (_Float16)v.w;
      *(unsigned long long*)(Wzh + i) = p.u;
    }
  } else if (bid < 194) {               // WcT[k][o] = (Wih@W4)[o][k]
    float* wih = (float*)smem;                 // 16*66
    float* w4s = (float*)(smem + 4224);        // 64*132
    const int o0 = (bid - 98) * 16;
    const int k = tid;
    float acc[16];
#pragma unroll
    for (int i = 0; i < 16; ++i) acc[i] = 0.f;
    for (int jc = 0; jc < 512; jc += 64) {
      __syncthreads();
      for (int idx = tid; idx < 16 * 64; idx += 256) {
        int oo = idx >> 6, jj = idx & 63;
        wih[oo * 66 + jj] = Wih[(o0 + oo) * 512 + jc + jj];
      }
      for (int idx = tid; idx < 64 * 131; idx += 256) {
        int r = idx / 131, c = idx - r * 131;
        w4s[r * 132 + c] = W4[(jc + r) * 131 + c];
      }
      __syncthreads();
      if (k < 131) {
        for (int jj = 0; jj < 64; ++jj) {
          float w4v = w4s[jj * 132 + k];
#pragma unroll
          for (int oo = 0; oo < 16; ++oo) acc[oo] += wih[oo * 66 + jj] * w4v;
        }
      }
    }
    if (k < 131) {
#pragma unroll
      for (int oo = 0; oo < 16; ++oo)
        WcT[k * 1536 + o0 + oo] = (_Float16)acc[oo];
    }
  } else {                              // w2h: 128 blocks, one batch row each
    float* dxa = (float*)smem;                 // 48*128 f32
    _Float16* w2t = (_Float16*)(smem + 24576); // 128*132 f16
    const int b = bid - 194;
    for (int idx = tid; idx < 48 * 128; idx += 256)
      dxa[idx] = dx[b * 6144 + idx];
    for (int hc = 0; hc < 4; ++hc) {
      __syncthreads();
      for (int idx = tid; idx < 128 * 128; idx += 256) {
        int hl = idx >> 7, i = idx & 127;
        w2t[i * 132 + hl] = (_Float16)W2[(hc * 128 + hl) * 128 + i];
      }
      __syncthreads();
      const int hh = tid & 127;
      const int tq = tid >> 7;
      const float b2v = b2[hc * 128 + hh];
      for (int tt = tq * 24; tt < tq * 24 + 24; ++tt) {
        float acc = b2v;
#pragma unroll 4
        for (int i = 0; i < 128; ++i)
          acc += dxa[tt * 128 + i] * (float)w2t[i * 132 + hh];
        w2h[(b * 48 + tt) * 512 + hc * 128 + hh] = (_Float16)acc;
      }
    }
  }
}

// ---------------- main persistent scan kernel ----------------
__global__ __launch_bounds__(256, 1) void decoder_main(
    const float* __restrict__ dx, const float* __restrict__ xin,
    const float* __restrict__ W3, const float* __restrict__ b3,
    const float* __restrict__ Wfc, const float* __restrict__ bfc,
    const _Float16* __restrict__ Wzh, const float* __restrict__ bz,
    const _Float16* __restrict__ WcT, const float* __restrict__ bc,
    const _Float16* __restrict__ w2h,
    float* __restrict__ hg, _Float16* __restrict__ hgh,
    float* __restrict__ zg, float* __restrict__ yg,
    unsigned int* __restrict__ bar, float* __restrict__ out)
{
  const int tid  = threadIdx.x;
  const int lane = tid & 63;
  const int wv   = tid >> 6;
  const int bid  = blockIdx.x;
  const int grp  = bid & 7;      // XCD-local heuristic (perf only)
  const int mem  = bid >> 3;     // 0..15
  const int b0   = grp * 16;
  const int myrow = b0 + mem;
  const int cb   = mem * 128;    // ph1 column base (of 2048)
  const int myIdx = grp * 16 + mem;
  const int base16 = grp * 16;
  unsigned int sync_no = 0;

  __shared__ float es[48];
  __shared__ float asx[48];
  __shared__ float ygs[16 * 132];
  __shared__ float wfcs[512];
  __shared__ float red[4];

  // ---- persistent per-lane state ----
  const int m = lane & 15, q = lane >> 4;
  // Wz B-fragments: wave handles 2 col-tiles of 16 -> 32 half8 (128 VGPRs)
  half8 wzf[2][16];
  int   ncol[2];
  float bzv[2];
#pragma unroll
  for (int t = 0; t < 2; ++t) {
    ncol[t] = cb + (wv * 2 + t) * 16 + m;
    const _Float16* wrow = Wzh + ncol[t] * 512 + q * 8;
#pragma unroll
    for (int ks = 0; ks < 16; ++ks)
      wzf[t][ks] = *(const half8*)(wrow + ks * 32);
    bzv[t] = bz[ncol[t]];
  }
  float w3r[8];
#pragma unroll
  for (int u = 0; u < 8; ++u) w3r[u] = W3[lane * 8 + u];
  for (int i = tid; i < 512; i += 256) wfcs[i] = Wfc[i];
  const float b3v  = b3[0];
  const float bfcv = bfc[0];
  // ph3 persistent: bias regs for this thread's 6 outputs
  const int m3  = tid >> 4;            // row 0..15
  const int cg  = tid & 15;
  const int c0  = mem * 32 + cg * 2;   // block owns h-cols [mem*32, +32)
  const float bc0 = bc[c0],        bc1 = bc[c0 + 1];
  const float bc2 = bc[512 + c0],  bc3 = bc[512 + c0 + 1];
  const float bc4 = bc[1024 + c0], bc5 = bc[1024 + c0 + 1];

  for (int step = 0; step < 48; ++step) {
    // ---- ph1: z[16,2048] = h @ [W1|W_hh]^T + bz  (MFMA, weights in regs) ----
    {
      half8 af[16];
      const _Float16* hrow = hgh + (b0 + m) * 512 + q * 8;
#pragma unroll
      for (int ks = 0; ks < 16; ++ks) {
        H8 t;
        t.u[0] = ld_u64(hrow + ks * 32);
        t.u[1] = ld_u64(hrow + ks * 32 + 4);
        af[ks] = t.h;
      }
#pragma unroll
      for (int t = 0; t < 2; ++t) {
        f32x4 acc = {bzv[t], bzv[t], bzv[t], bzv[t]};
#pragma unroll
        for (int ks = 0; ks < 16; ++ks)
          acc = __builtin_amdgcn_mfma_f32_16x16x32_f16(af[ks], wzf[t][ks], acc, 0, 0, 0);
#pragma unroll
        for (int r = 0; r < 4; ++r)
          st_f32(&zg[(b0 + q * 4 + r) * 2048 + ncol[t]], acc[r]);
      }
    }
    ++sync_no; flag_barrier(bar, myIdx, base16, sync_no, tid, lane, wv);

    // ---- ph2: e -> softmax -> c  (one batch row per block) ----
    {
      const int b = myrow;
      const float* __restrict__ zrow = zg + b * 2048;
      float w1r[8];
#pragma unroll
      for (int u2 = 0; u2 < 4; ++u2) {
        U2 t; t.u = ld_u64(zrow + lane * 8 + u2 * 2);
        w1r[u2 * 2] = t.f[0]; w1r[u2 * 2 + 1] = t.f[1];
      }
      const _Float16* __restrict__ w2row = w2h + b * 48 * 512 + lane * 8;
      for (int tt = 0; tt < 12; ++tt) {
        const int t = wv * 12 + tt;
        half8 w2v = *(const half8*)(w2row + t * 512);
        float p = 0.f;
#pragma unroll
        for (int u = 0; u < 8; ++u)
          p += w3r[u] * fast_tanh(w1r[u] + (float)w2v[u]);
#pragma unroll
        for (int off = 32; off >= 1; off >>= 1) p += __shfl_xor(p, off);
        if (lane == 0) es[t] = p + b3v;
      }
      __syncthreads();
      if (wv == 0) {
        float e = (lane < 48) ? es[lane] : -1e30f;
        float mx = e;
#pragma unroll
        for (int off = 32; off >= 1; off >>= 1) mx = fmaxf(mx, __shfl_xor(mx, off));
        float pe = (lane < 48) ? fexp2((e - mx) * 1.4426950408889634f) : 0.f;
        float s = pe;
#pragma unroll
        for (int off = 32; off >= 1; off >>= 1) s += __shfl_xor(s, off);
        float a = pe * frcp(s);
        if (lane < 48) {
          asx[lane] = a;
          if (step == 47) out[128 + b * 48 + lane] = a;   // alpha (last step)
        }
      }
      __syncthreads();
      if (tid < 128) {
        float acc = 0.f;
        const float* __restrict__ dxr = dx + b * 6144 + tid;
#pragma unroll 4
        for (int t = 0; t < 48; ++t) acc += asx[t] * dxr[t * 128];
        st_f32(&yg[b * 132 + tid], acc);                 // c
      } else if (tid < 131) {
        st_f32(&yg[b * 132 + tid], xin[(b * 48 + step) * 3 + (tid - 128)]);
      }
    }
    ++sync_no; flag_barrier(bar, myIdx, base16, sync_no, tid, lane, wv);

    // ---- ph3: gi = y@Wc^T + bc ; GRU gates ; h_new (col-sliced) ----
    {
      for (int i = tid; i < 16 * 66; i += 256) {
        unsigned long long u = ld_u64(yg + b0 * 132 + i * 2);
        *(unsigned long long*)&ygs[i * 2] = u;
      }
      __syncthreads();
      float a0 = bc0, a1 = bc1, a2 = bc2, a3 = bc3, a4 = bc4, a5 = bc5;
      const float* __restrict__ yrow = ygs + m3 * 132;
#pragma unroll 4
      for (int k = 0; k < 131; ++k) {
        const float yk = yrow[k];
        const _Float16* __restrict__ wr = WcT + k * 1536 + c0;
        h2v w0 = *(const h2v*)(wr);
        h2v w1v = *(const h2v*)(wr + 512);
        h2v w2v = *(const h2v*)(wr + 1024);
        a0 += yk * (float)w0[0];  a1 += yk * (float)w0[1];
        a2 += yk * (float)w1v[0]; a3 += yk * (float)w1v[1];
        a4 += yk * (float)w2v[0]; a5 += yk * (float)w2v[1];
      }
      const int b = b0 + m3;
      const float* __restrict__ zrow = zg + b * 2048;
      U2 tr, tz, tn2;
      tr.u  = ld_u64(zrow + 512 + c0);
      tz.u  = ld_u64(zrow + 1024 + c0);
      tn2.u = ld_u64(zrow + 1536 + c0);
      const float ho0 = hg[b * 512 + c0], ho1 = hg[b * 512 + c0 + 1];  // private
      const float r0 = fast_sigmoid(a0 + tr.f[0]), r1 = fast_sigmoid(a1 + tr.f[1]);
      const float z0 = fast_sigmoid(a2 + tz.f[0]), z1 = fast_sigmoid(a3 + tz.f[1]);
      const float n0 = fast_tanh(a4 + r0 * tn2.f[0]), n1 = fast_tanh(a5 + r1 * tn2.f[1]);
      const float hN0 = (1.f - z0) * n0 + z0 * ho0;
      const float hN1 = (1.f - z1) * n1 + z1 * ho1;
      hg[b * 512 + c0] = hN0;            // block-private, normal store
      hg[b * 512 + c0 + 1] = hN1;
      HU hp; hp.h[0] = (_Float16)hN0; hp.h[1] = (_Float16)hN1;
      st_u32((unsigned int*)(hgh + b * 512 + c0), hp.u);   // cross-block
    }
    ++sync_no; flag_barrier(bar, myIdx, base16, sync_no, tid, lane, wv);
  }

  // ---- epilogue: re[b] = h_f[b] . Wfc + bfc  (h from f16 coherent copy) ----
  {
    HU hu; hu.u = ld_u32((const unsigned int*)(hgh + myrow * 512 + tid * 2));
    float p = (float)hu.h[0] * wfcs[2 * tid] + (float)hu.h[1] * wfcs[2 * tid + 1];
#pragma unroll
    for (int off = 32; off >= 1; off >>= 1) p += __shfl_xor(p, off);
    if (lane == 0) red[wv] = p;
    __syncthreads();
    if (tid == 0) out[myrow] = red[0] + red[1] + red[2] + red[3] + bfcv;
  }
}

extern "C" void kernel_launch(void* const* d_in, const int* in_sizes, int n_in,
                              void* d_out, int out_size, void* d_ws, size_t ws_size,
                              hipStream_t stream) {
  (void)in_sizes; (void)n_in; (void)out_size; (void)ws_size;
  const float* dx  = (const float*)d_in[0];
  const float* xin = (const float*)d_in[1];
  const float* h0  = (const float*)d_in[2];
  const float* W1  = (const float*)d_in[3];
  const float* b1  = (const float*)d_in[4];
  const float* W2  = (const float*)d_in[5];
  const float* b2  = (const float*)d_in[6];
  const float* W3  = (const float*)d_in[7];
  const float* b3  = (const float*)d_in[8];
  const float* W4  = (const float*)d_in[9];
  const float* b4  = (const float*)d_in[10];
  const float* Wih = (const float*)d_in[11];
  const float* Whh = (const float*)d_in[12];
  const float* bih = (const float*)d_in[13];
  const float* bhh = (const float*)d_in[14];
  const float* Wfc = (const float*)d_in[15];
  const float* bfc = (const float*)d_in[16];

  char* ws = (char*)d_ws;
  unsigned int* bar = (unsigned int*)(ws + OFF_BAR);
  float*     bz  = (float*)(ws + OFF_BZ);
  float*     bc  = (float*)(ws + OFF_BC);
  _Float16*  Wzh = (_Float16*)(ws + OFF_WZ);
  _Float16*  WcT = (_Float16*)(ws + OFF_WCT);
  _Float16*  w2h = (_Float16*)(ws + OFF_W2H);
  float*     hg  = (float*)(ws + OFF_HG);
  _Float16*  hgh = (_Float16*)(ws + OFF_HGH);
  float*     zg  = (float*)(ws + OFF_ZG);
  float*     yg  = (float*)(ws + OFF_YG);

  prep_all<<<322, 256, 0, stream>>>(dx, h0, W1, Whh, b1, bhh, Wih, W4, b4, bih,
                                    W2, b2, hg, hgh, Wzh, bz, bc, WcT, w2h, bar);
  decoder_main<<<128, 256, 0, stream>>>(dx, xin, W3, b3, Wfc, bfc,
                                        Wzh, bz, WcT, bc, w2h,
                                        hg, hgh, zg, yg, bar, (float*)d_out);
}

// Round 5
// 1472.155 us; speedup vs baseline: 2.0149x; 1.2402x over previous
//
#include <hip/hip_runtime.h>

// B=128, T=48, I=128, H=512. Sequential 48-step attention+GRU scan.
// Persistent kernel: 8 groups x 16 blocks (grp = bid&7: XCD-local heuristic).
// R5: ALL-RELAXED sync (no release fence -> no buffer_wbl2 in the loop),
//     2 barriers/step (row-sliced fused ph2+ph3; y stays in LDS; h fp32 in regs).

typedef _Float16 half8 __attribute__((ext_vector_type(8)));
typedef _Float16 h2v  __attribute__((ext_vector_type(2)));
typedef float    f32x4 __attribute__((ext_vector_type(4)));

// ---------------- ws layout (bytes) ----------------
#define OFF_BAR   0u          // 128 flags * 128B (zeroed by prep)
#define OFF_BZ    32768u      // 2048 f32 : [b1 ; b_hh]
#define OFF_BC    40960u      // 1536 f32 : W_ih@b4 + b_ih
#define OFF_WZ    65536u      // 2048*512 f16 : [W1 ; W_hh] row-major
#define OFF_WCT   2162688u    // 131*1536 f16 : (W_ih@W4)^T, k-major
#define OFF_W2H   3178496u    // 128*48*512 f16 : dx@W2^T + b2
#define OFF_HGH   9732096u    // 128*512 f16 : h (cross-block copy)
#define OFF_ZG    9863168u    // 128*2048 f32 : z = [w1 | gh]

__device__ __forceinline__ float fexp2(float x) { return __builtin_amdgcn_exp2f(x); }
__device__ __forceinline__ float frcp(float x)  { return __builtin_amdgcn_rcpf(x); }
__device__ __forceinline__ float fast_tanh(float x) {
  x = fminf(fmaxf(x, -15.f), 15.f);
  float e = fexp2(x * 2.8853900817779268f);   // exp(2x)
  return (e - 1.f) * frcp(e + 1.f);
}
__device__ __forceinline__ float fast_sigmoid(float x) {
  x = fminf(fmaxf(x, -30.f), 30.f);
  float e = fexp2(x * 1.4426950408889634f);   // exp(x)
  return e * frcp(e + 1.f);
}

// ---- coherent (agent-scope sc-flagged, per-access) data movement ----
__device__ __forceinline__ void st_f32(float* p, float v) {
  __hip_atomic_store(p, v, __ATOMIC_RELAXED, __HIP_MEMORY_SCOPE_AGENT);
}
__device__ __forceinline__ unsigned long long ld_u64(const void* p) {
  return __hip_atomic_load((const unsigned long long*)p, __ATOMIC_RELAXED,
                           __HIP_MEMORY_SCOPE_AGENT);
}
__device__ __forceinline__ void st_u32(unsigned int* p, unsigned int v) {
  __hip_atomic_store(p, v, __ATOMIC_RELAXED, __HIP_MEMORY_SCOPE_AGENT);
}
union U2 { unsigned long long u; float f[2]; };
union H8 { unsigned long long u[2]; half8 h; };
union HU { unsigned int u; h2v h; };
union H4 { unsigned long long u; _Float16 h[4]; };

// All-relaxed flag barrier. Ordering: __syncthreads() emits s_waitcnt vmcnt(0)
// so all prior sc (write-through) stores are ACKED at the MALL before the flag
// store issues; readers poll/load sc -> always see MALL. No wbl2/inv anywhere.
__device__ __forceinline__ void flag_barrier(unsigned int* flags, int myIdx,
                                             int base16, unsigned int target,
                                             int tid, int lane, int wv) {
  __syncthreads();   // drains vmcnt: all sc stores acked at coherence point
  if (tid == 0)
    __hip_atomic_store(flags + myIdx * 32, target, __ATOMIC_RELAXED,
                       __HIP_MEMORY_SCOPE_AGENT);
  if (wv == 0) {
    unsigned int* fp = flags + (base16 + (lane & 15)) * 32;
    for (;;) {
      unsigned int v = (lane < 16)
        ? __hip_atomic_load(fp, __ATOMIC_RELAXED, __HIP_MEMORY_SCOPE_AGENT)
        : target;
      if ((__ballot(v < target) & 0xFFFFull) == 0) break;
      __builtin_amdgcn_s_sleep(1);
    }
    __asm__ __volatile__("" ::: "memory");
  }
  __syncthreads();
}

// ---------------- fused prep kernel (grid 322 x 256) ----------------
__global__ __launch_bounds__(256) void prep_all(
    const float* __restrict__ dx, const float* __restrict__ h0,
    const float* __restrict__ W1, const float* __restrict__ Whh,
    const float* __restrict__ b1, const float* __restrict__ bhh,
    const float* __restrict__ Wih, const float* __restrict__ W4,
    const float* __restrict__ b4, const float* __restrict__ bih,
    const float* __restrict__ W2, const float* __restrict__ b2,
    _Float16* __restrict__ hgh,
    _Float16* __restrict__ Wzh, float* __restrict__ bz,
    float* __restrict__ bc, _Float16* __restrict__ WcT,
    _Float16* __restrict__ w2h, unsigned int* __restrict__ bar)
{
  __shared__ __align__(16) char smem[58368];
  const int bid = blockIdx.x;
  const int tid = threadIdx.x;
  const int lane = tid & 63, wv = tid >> 6;

  if (bid == 0) {                       // zero flag region (8192 u32)
    for (int i = tid; i < 8192; i += 256) bar[i] = 0u;
  } else if (bid == 1) {                // bz
    for (int n = tid; n < 2048; n += 256)
      bz[n] = (n < 512) ? b1[n] : bhh[n - 512];
  } else if (bid < 18) {                // bc: 16 blocks x 96 rows, wave/row
    const int o0 = (bid - 2) * 96 + wv * 24;
    for (int it = 0; it < 24; ++it) {
      const int row = o0 + it;
      const float* r = Wih + row * 512 + lane * 8;
      float s = 0.f;
#pragma unroll
      for (int u = 0; u < 8; ++u) s += r[u] * b4[lane * 8 + u];
#pragma unroll
      for (int off = 32; off >= 1; off >>= 1) s += __shfl_xor(s, off);
      if (lane == 0) bc[row] = bih[row] + s;
    }
  } else if (bid < 34) {                // hgh init (f16 copy of h0)
    const int i0 = (bid - 18) * 4096 + tid * 16;
#pragma unroll
    for (int u = 0; u < 4; ++u) {
      float4 v = *(const float4*)(h0 + i0 + u * 4);
      H4 p; p.h[0] = (_Float16)v.x; p.h[1] = (_Float16)v.y;
      p.h[2] = (_Float16)v.z; p.h[3] = (_Float16)v.w;
      *(unsigned long long*)(hgh + i0 + u * 4) = p.u;
    }
  } else if (bid < 98) {                // Wzh = f16([W1;Whh]) flat copy
    const int i0 = (bid - 34) * 16384 + tid * 64;
#pragma unroll 4
    for (int u = 0; u < 16; ++u) {
      const int i = i0 + u * 4;
      const float* src = (i < 262144) ? (W1 + i) : (Whh + i - 262144);
      float4 v = *(const float4*)src;
      H4 p; p.h[0] = (_Float16)v.x; p.h[1] = (_Float16)v.y;
      p.h[2] = (_Float16)v.z; p.h[3] = (_Float16)v.w;
      *(unsigned long long*)(Wzh + i) = p.u;
    }
  } else if (bid < 194) {               // WcT[k][o] = (Wih@W4)[o][k]
    float* wih = (float*)smem;                 // 16*66
    float* w4s = (float*)(smem + 4224);        // 64*132
    const int o0 = (bid - 98) * 16;
    const int k = tid;
    float acc[16];
#pragma unroll
    for (int i = 0; i < 16; ++i) acc[i] = 0.f;
    for (int jc = 0; jc < 512; jc += 64) {
      __syncthreads();
      for (int idx = tid; idx < 16 * 64; idx += 256) {
        int oo = idx >> 6, jj = idx & 63;
        wih[oo * 66 + jj] = Wih[(o0 + oo) * 512 + jc + jj];
      }
      for (int idx = tid; idx < 64 * 131; idx += 256) {
        int r = idx / 131, c = idx - r * 131;
        w4s[r * 132 + c] = W4[(jc + r) * 131 + c];
      }
      __syncthreads();
      if (k < 131) {
        for (int jj = 0; jj < 64; ++jj) {
          float w4v = w4s[jj * 132 + k];
#pragma unroll
          for (int oo = 0; oo < 16; ++oo) acc[oo] += wih[oo * 66 + jj] * w4v;
        }
      }
    }
    if (k < 131) {
#pragma unroll
      for (int oo = 0; oo < 16; ++oo)
        WcT[k * 1536 + o0 + oo] = (_Float16)acc[oo];
    }
  } else {                              // w2h: 128 blocks, one batch row each
    float* dxa = (float*)smem;                 // 48*128 f32
    _Float16* w2t = (_Float16*)(smem + 24576); // 128*132 f16
    const int b = bid - 194;
    for (int idx = tid; idx < 48 * 128; idx += 256)
      dxa[idx] = dx[b * 6144 + idx];
    for (int hc = 0; hc < 4; ++hc) {
      __syncthreads();
      for (int idx = tid; idx < 128 * 128; idx += 256) {
        int hl = idx >> 7, i = idx & 127;
        w2t[i * 132 + hl] = (_Float16)W2[(hc * 128 + hl) * 128 + i];
      }
      __syncthreads();
      const int hh = tid & 127;
      const int tq = tid >> 7;
      const float b2v = b2[hc * 128 + hh];
      for (int tt = tq * 24; tt < tq * 24 + 24; ++tt) {
        float acc = b2v;
#pragma unroll 4
        for (int i = 0; i < 128; ++i)
          acc += dxa[tt * 128 + i] * (float)w2t[i * 132 + hh];
        w2h[(b * 48 + tt) * 512 + hc * 128 + hh] = (_Float16)acc;
      }
    }
  }
}

// ---------------- main persistent scan kernel ----------------
__global__ __launch_bounds__(256, 1) void decoder_main(
    const float* __restrict__ dx, const float* __restrict__ xin,
    const float* __restrict__ h0,
    const float* __restrict__ W3, const float* __restrict__ b3,
    const float* __restrict__ Wfc, const float* __restrict__ bfc,
    const _Float16* __restrict__ Wzh, const float* __restrict__ bz,
    const _Float16* __restrict__ WcT, const float* __restrict__ bc,
    const _Float16* __restrict__ w2h,
    _Float16* __restrict__ hgh, float* __restrict__ zg,
    unsigned int* __restrict__ bar, float* __restrict__ out)
{
  const int tid  = threadIdx.x;
  const int lane = tid & 63;
  const int wv   = tid >> 6;
  const int bid  = blockIdx.x;
  const int grp  = bid & 7;      // XCD-local heuristic (perf only)
  const int mem  = bid >> 3;     // 0..15
  const int b0   = grp * 16;
  const int myrow = b0 + mem;    // this block's row (ph2+ph3)
  const int cb   = mem * 128;    // ph1 column base (of 2048)
  const int myIdx = grp * 16 + mem;
  const int base16 = grp * 16;
  unsigned int sync_no = 0;

  __shared__ float es[48];
  __shared__ float asx[48];
  __shared__ float ysh[132];
  __shared__ float wfcs[512];
  __shared__ float red[4];

  // ---- persistent per-lane state ----
  const int m = lane & 15, q = lane >> 4;
  // ph1: Wz B-fragments, wave handles 2 col-tiles of 16 -> 32 half8 (128 VGPRs)
  half8 wzf[2][16];
  int   ncol[2];
  float bzv[2];
#pragma unroll
  for (int t = 0; t < 2; ++t) {
    ncol[t] = cb + (wv * 2 + t) * 16 + m;
    const _Float16* wrow = Wzh + ncol[t] * 512 + q * 8;
#pragma unroll
    for (int ks = 0; ks < 16; ++ks)
      wzf[t][ks] = *(const half8*)(wrow + ks * 32);
    bzv[t] = bz[ncol[t]];
  }
  float w3r[8];
#pragma unroll
  for (int u = 0; u < 8; ++u) w3r[u] = W3[lane * 8 + u];
  for (int i = tid; i < 512; i += 256) wfcs[i] = Wfc[i];
  const float b3v  = b3[0];
  const float bfcv = bfc[0];
  // ph3: this thread owns h-cols (2*tid, 2*tid+1) of row myrow
  const int c0 = tid * 2;
  const float bc0 = bc[c0],        bc1 = bc[c0 + 1];
  const float bc2 = bc[512 + c0],  bc3 = bc[512 + c0 + 1];
  const float bc4 = bc[1024 + c0], bc5 = bc[1024 + c0 + 1];
  // h fp32 master for own row lives in registers
  float hA = h0[myrow * 512 + c0];
  float hB = h0[myrow * 512 + c0 + 1];

  for (int step = 0; step < 48; ++step) {
    // ---- ph1: z[16,2048] = h @ [W1|W_hh]^T + bz  (MFMA, weights in regs) ----
    {
      half8 af[16];
      const _Float16* hrow = hgh + (b0 + m) * 512 + q * 8;
#pragma unroll
      for (int ks = 0; ks < 16; ++ks) {
        H8 t;
        t.u[0] = ld_u64(hrow + ks * 32);
        t.u[1] = ld_u64(hrow + ks * 32 + 4);
        af[ks] = t.h;
      }
#pragma unroll
      for (int t = 0; t < 2; ++t) {
        f32x4 acc = {bzv[t], bzv[t], bzv[t], bzv[t]};
#pragma unroll
        for (int ks = 0; ks < 16; ++ks)
          acc = __builtin_amdgcn_mfma_f32_16x16x32_f16(af[ks], wzf[t][ks], acc, 0, 0, 0);
#pragma unroll
        for (int r = 0; r < 4; ++r)
          st_f32(&zg[(b0 + q * 4 + r) * 2048 + ncol[t]], acc[r]);
      }
    }
    ++sync_no; flag_barrier(bar, myIdx, base16, sync_no, tid, lane, wv);

    // ---- ph2: e -> softmax -> c  (own row, block-local) ----
    const float* __restrict__ zrow = zg + myrow * 2048;
    {
      float w1r[8];
#pragma unroll
      for (int u2 = 0; u2 < 4; ++u2) {
        U2 t; t.u = ld_u64(zrow + lane * 8 + u2 * 2);
        w1r[u2 * 2] = t.f[0]; w1r[u2 * 2 + 1] = t.f[1];
      }
      const _Float16* __restrict__ w2row = w2h + myrow * 48 * 512 + lane * 8;
      for (int tt = 0; tt < 12; ++tt) {
        const int t = wv * 12 + tt;
        half8 w2v = *(const half8*)(w2row + t * 512);
        float p = 0.f;
#pragma unroll
        for (int u = 0; u < 8; ++u)
          p += w3r[u] * fast_tanh(w1r[u] + (float)w2v[u]);
#pragma unroll
        for (int off = 32; off >= 1; off >>= 1) p += __shfl_xor(p, off);
        if (lane == 0) es[t] = p + b3v;
      }
      __syncthreads();
      if (wv == 0) {
        float e = (lane < 48) ? es[lane] : -1e30f;
        float mx = e;
#pragma unroll
        for (int off = 32; off >= 1; off >>= 1) mx = fmaxf(mx, __shfl_xor(mx, off));
        float pe = (lane < 48) ? fexp2((e - mx) * 1.4426950408889634f) : 0.f;
        float s = pe;
#pragma unroll
        for (int off = 32; off >= 1; off >>= 1) s += __shfl_xor(s, off);
        float a = pe * frcp(s);
        if (lane < 48) {
          asx[lane] = a;
          if (step == 47) out[128 + myrow * 48 + lane] = a;   // alpha (last step)
        }
      }
      __syncthreads();
      if (tid < 128) {
        float acc = 0.f;
        const float* __restrict__ dxr = dx + myrow * 6144 + tid;
#pragma unroll 4
        for (int t = 0; t < 48; ++t) acc += asx[t] * dxr[t * 128];
        ysh[tid] = acc;                 // c (block-local!)
      } else if (tid < 131) {
        ysh[tid] = xin[(myrow * 48 + step) * 3 + (tid - 128)];
      }
      __syncthreads();
    }

    // ---- ph3: gi = y@Wc^T + bc ; GRU gates ; h_new (own row, full width) ----
    {
      float a0 = bc0, a1 = bc1, a2 = bc2, a3 = bc3, a4 = bc4, a5 = bc5;
#pragma unroll 4
      for (int k = 0; k < 131; ++k) {
        const float yk = ysh[k];
        const _Float16* __restrict__ wr = WcT + k * 1536 + c0;
        h2v w0 = *(const h2v*)(wr);
        h2v w1v = *(const h2v*)(wr + 512);
        h2v w2v = *(const h2v*)(wr + 1024);
        a0 += yk * (float)w0[0];  a1 += yk * (float)w0[1];
        a2 += yk * (float)w1v[0]; a3 += yk * (float)w1v[1];
        a4 += yk * (float)w2v[0]; a5 += yk * (float)w2v[1];
      }
      U2 tr, tz, tn2;
      tr.u  = ld_u64(zrow + 512 + c0);
      tz.u  = ld_u64(zrow + 1024 + c0);
      tn2.u = ld_u64(zrow + 1536 + c0);
      const float r0 = fast_sigmoid(a0 + tr.f[0]), r1 = fast_sigmoid(a1 + tr.f[1]);
      const float z0 = fast_sigmoid(a2 + tz.f[0]), z1 = fast_sigmoid(a3 + tz.f[1]);
      const float n0 = fast_tanh(a4 + r0 * tn2.f[0]), n1 = fast_tanh(a5 + r1 * tn2.f[1]);
      hA = (1.f - z0) * n0 + z0 * hA;
      hB = (1.f - z1) * n1 + z1 * hB;
      HU hp; hp.h[0] = (_Float16)hA; hp.h[1] = (_Float16)hB;
      st_u32((unsigned int*)(hgh + myrow * 512 + c0), hp.u);   // cross-block
    }
    ++sync_no; flag_barrier(bar, myIdx, base16, sync_no, tid, lane, wv);
  }

  // ---- epilogue: re[myrow] = h_f . Wfc + bfc  (h in registers) ----
  {
    float p = hA * wfcs[c0] + hB * wfcs[c0 + 1];
#pragma unroll
    for (int off = 32; off >= 1; off >>= 1) p += __shfl_xor(p, off);
    if (lane == 0) red[wv] = p;
    __syncthreads();
    if (tid == 0) out[myrow] = red[0] + red[1] + red[2] + red[3] + bfcv;
  }
}

extern "C" void kernel_launch(void* const* d_in, const int* in_sizes, int n_in,
                              void* d_out, int out_size, void* d_ws, size_t ws_size,
                              hipStream_t stream) {
  (void)in_sizes; (void)n_in; (void)out_size; (void)ws_size;
  const float* dx  = (const float*)d_in[0];
  const float* xin = (const float*)d_in[1];
  const float* h0  = (const float*)d_in[2];
  const float* W1  = (const float*)d_in[3];
  const float* b1  = (const float*)d_in[4];
  const float* W2  = (const float*)d_in[5];
  const float* b2  = (const float*)d_in[6];
  const float* W3  = (const float*)d_in[7];
  const float* b3  = (const float*)d_in[8];
  const float* W4  = (const float*)d_in[9];
  const float* b4  = (const float*)d_in[10];
  const float* Wih = (const float*)d_in[11];
  const float* Whh = (const float*)d_in[12];
  const float* bih = (const float*)d_in[13];
  const float* bhh = (const float*)d_in[14];
  const float* Wfc = (const float*)d_in[15];
  const float* bfc = (const float*)d_in[16];

  char* ws = (char*)d_ws;
  unsigned int* bar = (unsigned int*)(ws + OFF_BAR);
  float*     bz  = (float*)(ws + OFF_BZ);
  float*     bc  = (float*)(ws + OFF_BC);
  _Float16*  Wzh = (_Float16*)(ws + OFF_WZ);
  _Float16*  WcT = (_Float16*)(ws + OFF_WCT);
  _Float16*  w2h = (_Float16*)(ws + OFF_W2H);
  _Float16*  hgh = (_Float16*)(ws + OFF_HGH);
  float*     zg  = (float*)(ws + OFF_ZG);

  prep_all<<<322, 256, 0, stream>>>(dx, h0, W1, Whh, b1, bhh, Wih, W4, b4, bih,
                                    W2, b2, hgh, Wzh, bz, bc, WcT, w2h, bar);
  decoder_main<<<128, 256, 0, stream>>>(dx, xin, h0, W3, b3, Wfc, bfc,
                                        Wzh, bz, WcT, bc, w2h,
                                        hgh, zg, bar, (float*)d_out);
}